// Round 4
// baseline (1790.492 us; speedup 1.0000x reference)
//
#include <hip/hip_runtime.h>
#include <hip/hip_bf16.h>
#include <math.h>

// ---------------- problem constants ----------------
constexpr int NN   = 50000;        // nodes
constexpr int EE   = 400000;       // edges (before self loops)
constexpr int EP   = EE + NN;      // edges + self loops
constexpr int DIN  = 256;          // input dim
constexpr int M1   = 128;          // heads*H1
constexpr int F1   = 32;           // per-head dim layer 1
constexpr int H1N  = 4;            // heads layer 1
constexpr int M2   = 64;           // H2
constexpr int BP   = 4096;         // entity pairs
constexpr int DEC  = 512;          // decoder hidden
constexpr float SLOPE = 0.2f;

// output layout (flat, fp32)
constexpr int O_LOG    = 0;                      // [BP,2]
constexpr int O_RETOS  = 8192;                   // [NN,2]
constexpr int O_RETOSA = 108192;                 // [NN,2]
constexpr int O_X2     = 208192;                 // [NN,64]
constexpr int O_LOGITS = 3408192;                // [1,2NN]
constexpr int O_LOG1   = 3508192;                // [BP,2]

// ---------------- GEMM + attention-score fusion ----------------
// block = M threads, grid = NN blocks. H = X@W (fp32), AS/AD per (node, head).
__global__ void gemm_attn(const float* __restrict__ X,
                          const float* __restrict__ Wm,
                          const float* __restrict__ asrc, const float* __restrict__ adst,
                          float* __restrict__ Hout,
                          float* __restrict__ AS, float* __restrict__ AD,
                          int K, int M, int F){
    extern __shared__ float xs[];
    const int n = blockIdx.x;
    const int m = threadIdx.x;
    for (int k = m; k < K; k += M) xs[k] = X[(size_t)n*K + k];
    __syncthreads();
    float acc = 0.f;
    for (int k = 0; k < K; ++k) acc += xs[k] * Wm[(size_t)k*M + m];
    Hout[(size_t)n*M + m] = acc;
    float s1 = acc * asrc[m];
    float s2 = acc * adst[m];
    for (int o = F >> 1; o > 0; o >>= 1){
        s1 += __shfl_down(s1, o, F);
        s2 += __shfl_down(s2, o, F);
    }
    if ((m & (F-1)) == 0){
        int h = m / F;
        AS[(size_t)n*(M/F) + h] = s1;
        AD[(size_t)n*(M/F) + h] = s2;
    }
}

// one thread per (edge, feature column).
// Softmax WITHOUT max-subtraction: scores are O(+-10) so exp() is safe in fp32,
// and alpha = exp(e)/sum(exp(e)) is mathematically identical to the reference
// (the max-subtraction cancels).
__global__ void edge_scatter(const int* __restrict__ esrc, const int* __restrict__ edst,
                             const float* __restrict__ Hfeat,
                             const float* __restrict__ AS, const float* __restrict__ AD,
                             float* __restrict__ accum, float* __restrict__ denom,
                             int H, int M, int F, int total){
    int j = blockIdx.x*blockDim.x + threadIdx.x;
    if (j >= total) return;
    int i = j / M, m = j - i*M, h = m / F;
    int s = (i < EE) ? esrc[i] : (i - EE);
    int d = (i < EE) ? edst[i] : (i - EE);
    float e = AS[(size_t)s*H + h] + AD[(size_t)d*H + h];
    e = (e >= 0.f) ? e : SLOPE*e;
    float w = expf(e);
    atomicAdd(&accum[(size_t)d*M + m], Hfeat[(size_t)s*M + m] * w);
    if ((m & (F-1)) == 0) atomicAdd(&denom[(size_t)d*H + h], w);
}

// out = prelu(accum/(denom+eps) + b, p). Xout may alias accum (each thread
// touches only its own element).
__global__ void finalize_node(const float* accum, const float* denom,
                              const float* b, const float* p,
                              float* Xout, int M, int F, int total){
    int j = blockIdx.x*blockDim.x + threadIdx.x;
    if (j >= total) return;
    int n = j / M, m = j - n*M, h = m / F;
    float v = accum[j] / (denom[(size_t)n*(M/F) + h] + 1e-16f) + b[m];
    float pw = p[m];
    Xout[j] = (v >= 0.f) ? v : pw*v;
}

// column sums of x2 [NN,64] -> out[64]
__global__ void colsum(const float* __restrict__ X, float* __restrict__ out){
    __shared__ float red[256];
    const int c = blockIdx.x, t = threadIdx.x;
    float s = 0.f;
    for (int r = t; r < NN; r += 256) s += X[(size_t)r*64 + c];
    red[t] = s; __syncthreads();
    for (int o = 128; o > 0; o >>= 1){ if (t < o) red[t] += red[t+o]; __syncthreads(); }
    if (t == 0) out[c] = red[0];
}

// single block, 64 threads: summary vectors, bilinear Wc's, adv row-sums
__global__ void summary(const float* __restrict__ csum_o, const float* __restrict__ csum_a,
                        const float* __restrict__ mlpW, const float* __restrict__ mlpb,
                        const float* __restrict__ discW,
                        const float* __restrict__ advW, const float* __restrict__ advb,
                        float* __restrict__ Wc_o, float* __restrict__ Wc_a,
                        float* __restrict__ advRow, float* __restrict__ advbsum){
    __shared__ float s_o[64], s_a[64], h_o[64], h_a[64];
    const int t = threadIdx.x;
    s_o[t] = 1.f/(1.f + expf(-csum_o[t]/(float)NN));
    s_a[t] = 1.f/(1.f + expf(-csum_a[t]/(float)NN));
    __syncthreads();
    float ao = 0.f, aa = 0.f;
    for (int k = 0; k < 64; ++k){ float w = mlpW[k*64 + t]; ao += s_o[k]*w; aa += s_a[k]*w; }
    float bb = mlpb[t];
    h_o[t] = ao + bb; h_a[t] = aa + bb;
    __syncthreads();
    float wo = 0.f, wa = 0.f;
    for (int j = 0; j < 64; ++j){ float w = discW[t*64 + j]; wo += w*h_o[j]; wa += w*h_a[j]; }
    Wc_o[t] = wo; Wc_a[t] = wa;
    float ar = 0.f;
    for (int j = 0; j < 64; ++j) ar += advW[t*64 + j];
    advRow[t] = ar;
    float ab = advb[t];
    for (int o = 32; o > 0; o >>= 1) ab += __shfl_down(ab, o, 64);
    if (t == 0) advbsum[0] = ab;
}

// one wave (64 lanes) per node: 6 dot products + fp32 store of x2_o
__global__ void node_outputs(const float* __restrict__ x2o, const float* __restrict__ x2a,
                             const float* __restrict__ Wc_o, const float* __restrict__ Wc_a,
                             const float* __restrict__ advRow, const float* __restrict__ advbsum,
                             const float* __restrict__ discb,
                             float* __restrict__ out){
    const int n = blockIdx.x*4 + (threadIdx.x >> 6);
    const int l = threadIdx.x & 63;
    float xo = x2o[(size_t)n*64 + l], xa = x2a[(size_t)n*64 + l];
    float wo = Wc_o[l], wa = Wc_a[l], ar = advRow[l];
    float d1 = xo*wo, d2 = xa*wo, d3 = xa*wa, d4 = xo*wa, d5 = xo*ar, d6 = xa*ar;
    for (int o = 32; o > 0; o >>= 1){
        d1 += __shfl_down(d1, o, 64); d2 += __shfl_down(d2, o, 64);
        d3 += __shfl_down(d3, o, 64); d4 += __shfl_down(d4, o, 64);
        d5 += __shfl_down(d5, o, 64); d6 += __shfl_down(d6, o, 64);
    }
    out[O_X2 + (size_t)n*64 + l] = xo;
    if (l == 0){
        float db = discb[0];
        float ab = advbsum[0];
        out[O_RETOS  + n*2 + 0] = d1 + db;
        out[O_RETOS  + n*2 + 1] = d2 + db;
        out[O_RETOSA + n*2 + 0] = d3 + db;
        out[O_RETOSA + n*2 + 1] = d4 + db;
        out[O_LOGITS + n]       = d5 + ab;
        out[O_LOGITS + NN + n]  = d6 + ab;
    }
}

// fh = relu([x2[i0], x2[i1]] @ fW1 + fb1) : block per pair, 256 threads
__global__ void decoder1(const float* __restrict__ x2o, const int* __restrict__ idxArr,
                         const float* __restrict__ fW1, const float* __restrict__ fb1,
                         float* __restrict__ fh){
    __shared__ float e[128];
    const int b = blockIdx.x, t = threadIdx.x;
    const int i0 = idxArr[b], i1 = idxArr[BP + b];
    if (t < 64)        e[t] = x2o[(size_t)i0*64 + t];
    else if (t < 128)  e[t] = x2o[(size_t)i1*64 + (t - 64)];
    __syncthreads();
    for (int mm = t; mm < DEC; mm += 256){
        float acc = 0.f;
        for (int k = 0; k < 128; ++k) acc += e[k] * fW1[(size_t)k*DEC + mm];
        acc += fb1[mm];
        fh[(size_t)b*DEC + mm] = (acc > 0.f) ? acc : 0.f;
    }
}

// log / log1 heads: one wave per pair
__global__ void decoder2(const float* __restrict__ fh,
                         const float* __restrict__ fW2, const float* __restrict__ fb2,
                         const float* __restrict__ fW3, const float* __restrict__ fb3,
                         float* __restrict__ out){
    const int b = blockIdx.x, t = threadIdx.x;
    float a0 = 0.f, a1 = 0.f, c0 = 0.f, c1 = 0.f;
    for (int m = t; m < DEC; m += 64){
        float v = fh[(size_t)b*DEC + m];
        a0 += v*fW2[m*2 + 0]; a1 += v*fW2[m*2 + 1];
        c0 += v*fW3[m*2 + 0]; c1 += v*fW3[m*2 + 1];
    }
    for (int o = 32; o > 0; o >>= 1){
        a0 += __shfl_down(a0, o, 64); a1 += __shfl_down(a1, o, 64);
        c0 += __shfl_down(c0, o, 64); c1 += __shfl_down(c1, o, 64);
    }
    if (t == 0){
        out[O_LOG  + b*2 + 0] = a0 + fb2[0];
        out[O_LOG  + b*2 + 1] = a1 + fb2[1];
        out[O_LOG1 + b*2 + 0] = c0 + fb3[0];
        out[O_LOG1 + b*2 + 1] = c1 + fb3[1];
    }
}

extern "C" void kernel_launch(void* const* d_in, const int* in_sizes, int n_in,
                              void* d_out, int out_size, void* d_ws, size_t ws_size,
                              hipStream_t stream){
    const float* x_o    = (const float*)d_in[0];
    const float* x_a    = (const float*)d_in[1];
    const int*   edge   = (const int*)d_in[2];
    const int*   idxp   = (const int*)d_in[3];
    const float* W1     = (const float*)d_in[4];
    const float* a_src1 = (const float*)d_in[5];
    const float* a_dst1 = (const float*)d_in[6];
    const float* b1     = (const float*)d_in[7];
    const float* p1     = (const float*)d_in[8];
    const float* W2     = (const float*)d_in[9];
    const float* a_src2 = (const float*)d_in[10];
    const float* a_dst2 = (const float*)d_in[11];
    const float* b2     = (const float*)d_in[12];
    const float* p2     = (const float*)d_in[13];
    const float* mlpW   = (const float*)d_in[14];
    const float* mlpb   = (const float*)d_in[15];
    const float* discW  = (const float*)d_in[16];
    const float* discb  = (const float*)d_in[17];
    const float* advW   = (const float*)d_in[18];
    const float* advb   = (const float*)d_in[19];
    const float* fW1    = (const float*)d_in[20];
    const float* fb1    = (const float*)d_in[21];
    const float* fW2    = (const float*)d_in[22];
    const float* fb2    = (const float*)d_in[23];
    const float* fW3    = (const float*)d_in[24];
    const float* fb3    = (const float*)d_in[25];

    const int* esrc = edge;
    const int* edst = edge + EE;

    // workspace carve-up (fp32), ~78 MB total
    float* w = (float*)d_ws;
    size_t off = 0;
    auto alloc = [&](size_t nfloats){ float* p = w + off; off += nfloats; return p; };
    float* accum = alloc((size_t)NN * M1);   // scatter accumulator; x1b aliases (in-place)
    float* hbuf  = alloc((size_t)NN * M1);   // H = X@W; fh aliases after encoders
    float* asb   = alloc((size_t)NN * H1N);
    float* adb   = alloc((size_t)NN * H1N);
    float* denom = alloc((size_t)NN * H1N);
    float* x2o   = alloc((size_t)NN * M2);
    float* x2a   = alloc((size_t)NN * M2);
    float* smallb= alloc(512);
    float* x1b    = accum;                 // layer-1 finalize runs in-place
    float* fh     = hbuf;                  // decoder scratch after encoders done
    float* csum_o = smallb;       float* csum_a = smallb + 64;
    float* Wc_o   = smallb + 128; float* Wc_a   = smallb + 192;
    float* advRow = smallb + 256; float* advbs  = smallb + 320;

    float* out = (float*)d_out;

    auto run_encoder = [&](const float* xin, float* x2out){
        // ---- layer 1: D=256 -> 4 heads x 32 ----
        gemm_attn<<<NN, M1, DIN*sizeof(float), stream>>>(
            xin, W1, a_src1, a_dst1, hbuf, asb, adb, DIN, M1, F1);
        hipMemsetAsync(denom, 0, (size_t)NN*H1N*sizeof(float), stream);
        hipMemsetAsync(accum, 0, (size_t)NN*M1*sizeof(float), stream);
        {
            int tot = EP * M1;   // 57.6M
            edge_scatter<<<(tot + 255)/256, 256, 0, stream>>>(esrc, edst, hbuf, asb, adb,
                                                              accum, denom, H1N, M1, F1, tot);
        }
        finalize_node<<<(NN*M1 + 255)/256, 256, 0, stream>>>(accum, denom, b1, p1,
                                                             x1b, M1, F1, NN*M1);

        // ---- layer 2: 128 -> 64, 1 head ----
        gemm_attn<<<NN, M2, M1*sizeof(float), stream>>>(
            x1b, W2, a_src2, a_dst2, hbuf, asb, adb, M1, M2, M2);
        hipMemsetAsync(denom, 0, (size_t)NN*sizeof(float), stream);
        hipMemsetAsync(accum, 0, (size_t)NN*M2*sizeof(float), stream);
        {
            int tot = EP * M2;   // 28.8M
            edge_scatter<<<(tot + 255)/256, 256, 0, stream>>>(esrc, edst, hbuf, asb, adb,
                                                              accum, denom, 1, M2, M2, tot);
        }
        finalize_node<<<(NN*M2 + 255)/256, 256, 0, stream>>>(accum, denom, b2, p2,
                                                             x2out, M2, M2, NN*M2);
    };

    run_encoder(x_o, x2o);
    run_encoder(x_a, x2a);

    colsum<<<64, 256, 0, stream>>>(x2o, csum_o);
    colsum<<<64, 256, 0, stream>>>(x2a, csum_a);
    summary<<<1, 64, 0, stream>>>(csum_o, csum_a, mlpW, mlpb, discW, advW, advb,
                                  Wc_o, Wc_a, advRow, advbs);
    node_outputs<<<NN/4, 256, 0, stream>>>(x2o, x2a, Wc_o, Wc_a, advRow, advbs, discb, out);
    decoder1<<<BP, 256, 0, stream>>>(x2o, idxp, fW1, fb1, fh);
    decoder2<<<BP, 64, 0, stream>>>(fh, fW2, fb2, fW3, fb3, out);
}